// Round 4
// baseline (892.244 us; speedup 1.0000x reference)
//
#include <hip/hip_runtime.h>
#include <hip/hip_bf16.h>
#include <hip/hip_fp16.h>

#define NCELL 64
#define CIN 8
#define EE 4
#define DD 4
#define HH 256
#define WW 256

#define TW 32
#define TH 16
#define ZW (TW + 4)   // 36
#define ZH (TH + 4)   // 20
#define HW1 (TW + 2)  // 34
#define HH1 (TH + 2)  // 18
#define NCG 4         // cells per block in edge pass

// workspace layout (float4 indices into wt section)
#define W_DOWN 0
#define W_E1   8
#define W_E2   44
#define W_UP   80
#define W_N1   84
#define W_N2   192
#define W_R    228
#define W_TOTAL 236

#define COMP(v,i) ((i)==0?(v).x:(i)==1?(v).y:(i)==2?(v).z:(v).w)

__device__ __forceinline__ void fma4(float4& a, float s, float4 w) {
    a.x = fmaf(s, w.x, a.x);
    a.y = fmaf(s, w.y, a.y);
    a.z = fmaf(s, w.z, a.z);
    a.w = fmaf(s, w.w, a.w);
}

__device__ __forceinline__ float silu1(float v) { return v / (1.0f + __expf(-v)); }
__device__ __forceinline__ float4 silu4(float4 v) {
    return make_float4(silu1(v.x), silu1(v.y), silu1(v.z), silu1(v.w));
}

__device__ __forceinline__ unsigned int pk2(float a, float b) {
    __half2 h = __floats2half2_rn(a, b);
    return __builtin_bit_cast(unsigned int, h);
}
__device__ __forceinline__ float2 upk2(unsigned int u) {
    __half2 h = __builtin_bit_cast(__half2, u);
    return __half22float2(h);
}
__device__ __forceinline__ uint2 pk4(float4 v) {
    return make_uint2(pk2(v.x, v.y), pk2(v.z, v.w));
}

// 3x3 conv over f16-packed LDS plane (uint2 = 4 input channels), f32 accumulate,
// for a vertical pair of output pixels (ly0, ly0+1) at column lx.
// wt: [ci*9 + dy*3 + dx] -> float4 of 4 output-channel weights (pre-transposed).
template<int LW>
__device__ __forceinline__ void conv3x3_pair_h(const uint2 (*in)[LW], int ly0, int lx,
                                               const float4* __restrict__ wt,
                                               float4& s0, float4& s1) {
#pragma unroll
    for (int dx = 0; dx < 3; ++dx) {
        float2 a[4][2];
#pragma unroll
        for (int r = 0; r < 4; ++r) {
            const uint2 v = in[ly0 + r][lx + dx];
            a[r][0] = upk2(v.x);
            a[r][1] = upk2(v.y);
        }
#pragma unroll
        for (int dy = 0; dy < 3; ++dy) {
#pragma unroll
            for (int ci = 0; ci < 4; ++ci) {
                const float4 w4 = wt[ci * 9 + dy * 3 + dx];
                const float e0 = (ci < 2) ? (ci == 0 ? a[dy][0].x : a[dy][0].y)
                                          : (ci == 2 ? a[dy][1].x : a[dy][1].y);
                const float e1 = (ci < 2) ? (ci == 0 ? a[dy + 1][0].x : a[dy + 1][0].y)
                                          : (ci == 2 ? a[dy + 1][1].x : a[dy + 1][1].y);
                fma4(s0, e0, w4);
                fma4(s1, e1, w4);
            }
        }
    }
}

__global__ __launch_bounds__(256) void zero_kernel(float* __restrict__ p) {
    int i = blockIdx.x * 256 + threadIdx.x;
    reinterpret_cast<float4*>(p)[i] = make_float4(0.f, 0.f, 0.f, 0.f);
}

// transpose weights to [ci][tap] -> float4-of-out-channels layout
__global__ __launch_bounds__(128) void prep_kernel(
    const float* __restrict__ wd, const float* __restrict__ we1,
    const float* __restrict__ we2, const float* __restrict__ wu,
    const float* __restrict__ wn1, const float* __restrict__ wn2,
    const float* __restrict__ wr, float4* __restrict__ wt) {
    const int t = threadIdx.x;
    if (t < 8)   wt[W_DOWN + t] = make_float4(wd[t], wd[8 + t], wd[16 + t], wd[24 + t]);
    if (t < 36)  wt[W_E1 + t]   = make_float4(we1[t], we1[36 + t], we1[72 + t], we1[108 + t]);
    if (t < 36)  wt[W_E2 + t]   = make_float4(we2[t], we2[36 + t], we2[72 + t], we2[108 + t]);
    if (t < 4)   wt[W_UP + t]   = make_float4(wu[t], wu[4 + t], wu[8 + t], wu[12 + t]);
    if (t < 108) wt[W_N1 + t]   = make_float4(wn1[t], wn1[108 + t], wn1[216 + t], wn1[324 + t]);
    if (t < 36)  wt[W_N2 + t]   = make_float4(wn2[t], wn2[36 + t], wn2[72 + t], wn2[108 + t]);
    if (t < 8)   wt[W_R + t]    = make_float4(wr[t], wr[8 + t], wr[16 + t], wr[24 + t]);
}

__global__ __launch_bounds__(256) void edge_kernel(
    const float* __restrict__ x, const float4* __restrict__ wt,
    const float* __restrict__ b_down, const float* __restrict__ b_e1,
    const float* __restrict__ b_e2,
    float* __restrict__ A)   // pixel-major: A[(y*WW+x)*4 + e]
{
    __shared__ uint2 zb[ZH][ZW];     // 5.6 KB
    __shared__ uint2 h1b[HH1][HW1];  // 4.8 KB

    const int tid = threadIdx.x;
    const int ox = blockIdx.x * TW;
    const int oy = blockIdx.y * TH;
    const int n0 = blockIdx.z * NCG;

    const float4* wt_down = wt + W_DOWN;
    const float4* wt_e1 = wt + W_E1;
    const float4* wt_e2 = wt + W_E2;

    const float4 bdn = make_float4(b_down[0], b_down[1], b_down[2], b_down[3]);
    const float4 be1 = make_float4(b_e1[0], b_e1[1], b_e1[2], b_e1[3]);
    const float4 be2 = make_float4(b_e2[0], b_e2[1], b_e2[2], b_e2[3]);

    float4 acc0 = make_float4(0.f, 0.f, 0.f, 0.f);
    float4 acc1 = make_float4(0.f, 0.f, 0.f, 0.f);

    for (int j = 0; j < NCG; ++j) {
        const int n = n0 + j;
        const float* __restrict__ xn = x + (size_t)n * CIN * HH * WW;

        // ---- z = 1x1 down conv over halo-2 region (uniform trip count) ----
#pragma unroll
        for (int it = 0; it < 3; ++it) {
            int idx = tid + it * 256;
            idx = idx < ZH * ZW ? idx : ZH * ZW - 1;   // clamp: benign duplicate
            const int ly = idx / ZW, lx = idx - (idx / ZW) * ZW;
            const int gy = oy + ly - 2, gx = ox + lx - 2;
            float4 zv = make_float4(0.f, 0.f, 0.f, 0.f);
            if ((unsigned)gy < (unsigned)HH && (unsigned)gx < (unsigned)WW) {
                zv = bdn;
#pragma unroll
                for (int c = 0; c < CIN; ++c)
                    fma4(zv, xn[(c * HH + gy) * WW + gx], wt_down[c]);
            }
            zb[ly][lx] = pk4(zv);
        }
        __syncthreads();

        // ---- h1 = silu(3x3 e1) over halo-1 region: 9 row-pairs x 34 cols ----
#pragma unroll
        for (int it = 0; it < 2; ++it) {
            int t = tid + it * 256;
            t = t < 9 * HW1 ? t : 9 * HW1 - 1;          // clamp: benign duplicate
            const int pr = t / HW1;
            const int lx = t - pr * HW1;
            const int ly0 = pr * 2;
            float4 s0 = be1, s1 = be1;
            conv3x3_pair_h<ZW>(zb, ly0, lx, wt_e1, s0, s1);
            const int gx = ox + lx - 1;
            const int gy0 = oy + ly0 - 1;
            const bool xok = (unsigned)gx < (unsigned)WW;
            const float4 z4 = make_float4(0.f, 0.f, 0.f, 0.f);
            const float4 v0 = (xok && (unsigned)(gy0 + 0) < (unsigned)HH) ? silu4(s0) : z4;
            const float4 v1 = (xok && (unsigned)(gy0 + 1) < (unsigned)HH) ? silu4(s1) : z4;
            h1b[ly0 + 0][lx] = pk4(v0);
            h1b[ly0 + 1][lx] = pk4(v1);
        }
        __syncthreads();

        // ---- h2 = silu(3x3 e2) over 8 row-pairs x 32 cols (exact 256), accumulate ----
        {
            const int py0 = (tid >> 5) * 2;
            const int px = tid & 31;
            float4 s0 = be2, s1 = be2;
            conv3x3_pair_h<HW1>(h1b, py0, px, wt_e2, s0, s1);
            const float4 v0 = silu4(s0), v1 = silu4(s1);
            acc0.x += v0.x; acc0.y += v0.y; acc0.z += v0.z; acc0.w += v0.w;
            acc1.x += v1.x; acc1.y += v1.y; acc1.z += v1.z; acc1.w += v1.w;
        }
        __syncthreads();
    }

    // ---- atomic accumulate into A (pixel-major) ----
    const int py0 = (tid >> 5) * 2;
    const int px = tid & 31;
    const int gy0 = oy + py0, gx = ox + px;
    float* a0 = &A[((size_t)(gy0 + 0) * WW + gx) * 4];
    float* a1 = &A[((size_t)(gy0 + 1) * WW + gx) * 4];
    atomicAdd(a0 + 0, acc0.x); atomicAdd(a0 + 1, acc0.y);
    atomicAdd(a0 + 2, acc0.z); atomicAdd(a0 + 3, acc0.w);
    atomicAdd(a1 + 0, acc1.x); atomicAdd(a1 + 1, acc1.y);
    atomicAdd(a1 + 2, acc1.z); atomicAdd(a1 + 3, acc1.w);
}

__global__ __launch_bounds__(256) void node_kernel(
    const float* __restrict__ x, const float* __restrict__ A,
    const float4* __restrict__ wt,
    const float* __restrict__ b_up, const float* __restrict__ b_n1,
    const float* __restrict__ b_n2, const float* __restrict__ b_r,
    float* __restrict__ out)
{
    __shared__ uint2 xa[3][ZH][ZW];   // 16.9 KB: {x0-3, x4-7, Aup0-3} f16-packed
    __shared__ uint2 y1b[HH1][HW1];   // 4.8 KB

    const int tid = threadIdx.x;
    const int ox = blockIdx.x * TW;
    const int oy = blockIdx.y * TH;
    const int n = blockIdx.z;
    const float* __restrict__ xn = x + (size_t)n * CIN * HH * WW;

    const float4* wt_up = wt + W_UP;
    const float4* wt_n1 = wt + W_N1;
    const float4* wt_n2 = wt + W_N2;
    const float4* wt_r  = wt + W_R;

    const float4 bup = make_float4(b_up[0], b_up[1], b_up[2], b_up[3]);
    const float4 bn1 = make_float4(b_n1[0], b_n1[1], b_n1[2], b_n1[3]);
    const float4 bn2r = make_float4(b_n2[0] + b_r[0], b_n2[1] + b_r[1],
                                    b_n2[2] + b_r[2], b_n2[3] + b_r[3]);

    // ---- stage [x || up(A)] tile with halo 2, fusing the 1x1 up conv ----
#pragma unroll
    for (int it = 0; it < 3; ++it) {
        int idx = tid + it * 256;
        idx = idx < ZH * ZW ? idx : ZH * ZW - 1;       // clamp: benign duplicate
        const int ly = idx / ZW, lx = idx - (idx / ZW) * ZW;
        const int gy = oy + ly - 2, gx = ox + lx - 2;
        float4 g0 = make_float4(0.f, 0.f, 0.f, 0.f);
        float4 g1 = g0, au = g0;
        if ((unsigned)gy < (unsigned)HH && (unsigned)gx < (unsigned)WW) {
            g0 = make_float4(xn[(0 * HH + gy) * WW + gx], xn[(1 * HH + gy) * WW + gx],
                             xn[(2 * HH + gy) * WW + gx], xn[(3 * HH + gy) * WW + gx]);
            g1 = make_float4(xn[(4 * HH + gy) * WW + gx], xn[(5 * HH + gy) * WW + gx],
                             xn[(6 * HH + gy) * WW + gx], xn[(7 * HH + gy) * WW + gx]);
            const float4 a4 = reinterpret_cast<const float4*>(A)[gy * WW + gx];
            au = bup;
#pragma unroll
            for (int e = 0; e < 4; ++e) fma4(au, COMP(a4, e), wt_up[e]);
        }
        xa[0][ly][lx] = pk4(g0);
        xa[1][ly][lx] = pk4(g1);
        xa[2][ly][lx] = pk4(au);
    }
    __syncthreads();

    // ---- y1 = silu(3x3 n1, 12->4) over 9 row-pairs x 34 cols ----
#pragma unroll
    for (int it = 0; it < 2; ++it) {
        int t = tid + it * 256;
        t = t < 9 * HW1 ? t : 9 * HW1 - 1;              // clamp: benign duplicate
        const int pr = t / HW1;
        const int lx = t - pr * HW1;
        const int ly0 = pr * 2;
        float4 s0 = bn1, s1 = bn1;
        conv3x3_pair_h<ZW>(xa[0], ly0, lx, wt_n1, s0, s1);
        conv3x3_pair_h<ZW>(xa[1], ly0, lx, wt_n1 + 36, s0, s1);
        conv3x3_pair_h<ZW>(xa[2], ly0, lx, wt_n1 + 72, s0, s1);
        const int gx = ox + lx - 1;
        const int gy0 = oy + ly0 - 1;
        const bool xok = (unsigned)gx < (unsigned)WW;
        const float4 z4 = make_float4(0.f, 0.f, 0.f, 0.f);
        const float4 v0 = (xok && (unsigned)(gy0 + 0) < (unsigned)HH) ? silu4(s0) : z4;
        const float4 v1 = (xok && (unsigned)(gy0 + 1) < (unsigned)HH) ? silu4(s1) : z4;
        y1b[ly0 + 0][lx] = pk4(v0);
        y1b[ly0 + 1][lx] = pk4(v1);
    }
    __syncthreads();

    // ---- out = 3x3 n2 (y1) + 1x1 r (x), 8 row-pairs x 32 cols (exact 256) ----
    {
        const int py0 = (tid >> 5) * 2;
        const int px = tid & 31;
        float4 s0 = bn2r, s1 = bn2r;
        conv3x3_pair_h<HW1>(y1b, py0, px, wt_n2, s0, s1);
        // residual 1x1 on x (groups 0,1), tile-center offset +2
#pragma unroll
        for (int g = 0; g < 2; ++g) {
            const uint2 c0 = xa[g][py0 + 2][px + 2];
            const uint2 c1 = xa[g][py0 + 3][px + 2];
            const float2 c0lo = upk2(c0.x), c0hi = upk2(c0.y);
            const float2 c1lo = upk2(c1.x), c1hi = upk2(c1.y);
            fma4(s0, c0lo.x, wt_r[g * 4 + 0]); fma4(s1, c1lo.x, wt_r[g * 4 + 0]);
            fma4(s0, c0lo.y, wt_r[g * 4 + 1]); fma4(s1, c1lo.y, wt_r[g * 4 + 1]);
            fma4(s0, c0hi.x, wt_r[g * 4 + 2]); fma4(s1, c1hi.x, wt_r[g * 4 + 2]);
            fma4(s0, c0hi.y, wt_r[g * 4 + 3]); fma4(s1, c1hi.y, wt_r[g * 4 + 3]);
        }
        const int gy0 = oy + py0, gx = ox + px;
#pragma unroll
        for (int o = 0; o < 4; ++o) {
            out[(((size_t)n * DD + o) * HH + gy0 + 0) * WW + gx] = COMP(s0, o);
            out[(((size_t)n * DD + o) * HH + gy0 + 1) * WW + gx] = COMP(s1, o);
        }
    }
}

extern "C" void kernel_launch(void* const* d_in, const int* in_sizes, int n_in,
                              void* d_out, int out_size, void* d_ws, size_t ws_size,
                              hipStream_t stream) {
    const float* x      = (const float*)d_in[0];
    const float* w_down = (const float*)d_in[1];
    const float* b_down = (const float*)d_in[2];
    const float* w_e1   = (const float*)d_in[3];
    const float* b_e1   = (const float*)d_in[4];
    const float* w_e2   = (const float*)d_in[5];
    const float* b_e2   = (const float*)d_in[6];
    const float* w_up   = (const float*)d_in[7];
    const float* b_up   = (const float*)d_in[8];
    const float* w_n1   = (const float*)d_in[9];
    const float* b_n1   = (const float*)d_in[10];
    const float* w_n2   = (const float*)d_in[11];
    const float* b_n2   = (const float*)d_in[12];
    const float* w_r    = (const float*)d_in[13];
    const float* b_r    = (const float*)d_in[14];
    float* out = (float*)d_out;

    float* A = (float*)d_ws;                               // 1 MiB, pixel-major
    float4* wt = (float4*)((float*)d_ws + 4 * HH * WW);    // 236 float4

    zero_kernel<<<dim3(256), dim3(256), 0, stream>>>(A);
    prep_kernel<<<dim3(1), dim3(128), 0, stream>>>(w_down, w_e1, w_e2, w_up,
                                                   w_n1, w_n2, w_r, wt);

    edge_kernel<<<dim3(WW / TW, HH / TH, NCELL / NCG), dim3(256), 0, stream>>>(
        x, wt, b_down, b_e1, b_e2, A);

    node_kernel<<<dim3(WW / TW, HH / TH, NCELL), dim3(256), 0, stream>>>(
        x, A, wt, b_up, b_n1, b_n2, b_r, out);
}

// Round 5
// 663.538 us; speedup vs baseline: 1.3447x; 1.3447x over previous
//
#include <hip/hip_runtime.h>
#include <hip/hip_bf16.h>

#define NCELL 64
#define CIN 8
#define EE 4
#define DD 4
#define HH 256
#define WW 256

#define TW 32
#define TH 16
#define ZW (TW + 4)   // 36
#define ZH (TH + 4)   // 20
#define HW1 (TW + 2)  // 34
#define HH1 (TH + 2)  // 18
#define NCG 4         // cells per block in edge pass

// workspace layout (float4 indices into wt section)
#define W_DOWN 0
#define W_E1   8
#define W_E2   44
#define W_UP   80
#define W_N1   84
#define W_N2   192
#define W_R    228
#define W_TOTAL 236

#define COMP(v,i) ((i)==0?(v).x:(i)==1?(v).y:(i)==2?(v).z:(v).w)

__device__ __forceinline__ void fma4(float4& a, float s, float4 w) {
    a.x = fmaf(s, w.x, a.x);
    a.y = fmaf(s, w.y, a.y);
    a.z = fmaf(s, w.z, a.z);
    a.w = fmaf(s, w.w, a.w);
}

__device__ __forceinline__ float silu1(float v) { return v / (1.0f + __expf(-v)); }
__device__ __forceinline__ float4 silu4(float4 v) {
    return make_float4(silu1(v.x), silu1(v.y), silu1(v.z), silu1(v.w));
}

// 3x3 conv, 4 packed input channels, 4 packed output channels, vertical pixel
// pair (ly0, ly0+1) at column lx. in: LDS float4 plane, row width LW.
// wt: pre-transposed taps, wt[ci*9 + dy*3 + dx] = float4 of 4 out-channel weights.
template<int LW>
__device__ __forceinline__ void conv3x3_pair(const float4 (*in)[LW], int ly0, int lx,
                                             const float4* __restrict__ wt,
                                             float4& s0, float4& s1) {
#pragma unroll
    for (int dx = 0; dx < 3; ++dx) {
        const float4 a0 = in[ly0 + 0][lx + dx];
        const float4 a1 = in[ly0 + 1][lx + dx];
        const float4 a2 = in[ly0 + 2][lx + dx];
        const float4 a3 = in[ly0 + 3][lx + dx];
#pragma unroll
        for (int dy = 0; dy < 3; ++dy) {
            const float4 va = (dy == 0) ? a0 : (dy == 1) ? a1 : a2;
            const float4 vb = (dy == 0) ? a1 : (dy == 1) ? a2 : a3;
#pragma unroll
            for (int ci = 0; ci < 4; ++ci) {
                const float4 w4 = wt[ci * 9 + dy * 3 + dx];
                fma4(s0, COMP(va, ci), w4);
                fma4(s1, COMP(vb, ci), w4);
            }
        }
    }
}

__global__ __launch_bounds__(256) void zero_kernel(float* __restrict__ p) {
    int i = blockIdx.x * 256 + threadIdx.x;
    reinterpret_cast<float4*>(p)[i] = make_float4(0.f, 0.f, 0.f, 0.f);
}

// transpose weights to [ci][tap] -> float4-of-out-channels layout
__global__ __launch_bounds__(128) void prep_kernel(
    const float* __restrict__ wd, const float* __restrict__ we1,
    const float* __restrict__ we2, const float* __restrict__ wu,
    const float* __restrict__ wn1, const float* __restrict__ wn2,
    const float* __restrict__ wr, float4* __restrict__ wt) {
    const int t = threadIdx.x;
    if (t < 8)   wt[W_DOWN + t] = make_float4(wd[t], wd[8 + t], wd[16 + t], wd[24 + t]);
    if (t < 36)  wt[W_E1 + t]   = make_float4(we1[t], we1[36 + t], we1[72 + t], we1[108 + t]);
    if (t < 36)  wt[W_E2 + t]   = make_float4(we2[t], we2[36 + t], we2[72 + t], we2[108 + t]);
    if (t < 4)   wt[W_UP + t]   = make_float4(wu[t], wu[4 + t], wu[8 + t], wu[12 + t]);
    if (t < 108) wt[W_N1 + t]   = make_float4(wn1[t], wn1[108 + t], wn1[216 + t], wn1[324 + t]);
    if (t < 36)  wt[W_N2 + t]   = make_float4(wn2[t], wn2[36 + t], wn2[72 + t], wn2[108 + t]);
    if (t < 8)   wt[W_R + t]    = make_float4(wr[t], wr[8 + t], wr[16 + t], wr[24 + t]);
}

__global__ __launch_bounds__(256) void edge_kernel(
    const float* __restrict__ x, const float4* __restrict__ wt,
    const float* __restrict__ b_down, const float* __restrict__ b_e1,
    const float* __restrict__ b_e2,
    float* __restrict__ A)   // pixel-major: A[(y*WW+x)*4 + e]
{
    __shared__ float4 zb[ZH][ZW];     // 11.25 KB
    __shared__ float4 h1b[HH1][HW1];  // 9.56 KB

    const int tid = threadIdx.x;
    const int ox = blockIdx.x * TW;
    const int oy = blockIdx.y * TH;
    const int n0 = blockIdx.z * NCG;

    const float4* wt_down = wt + W_DOWN;
    const float4* wt_e1 = wt + W_E1;
    const float4* wt_e2 = wt + W_E2;

    const float4 bdn = make_float4(b_down[0], b_down[1], b_down[2], b_down[3]);
    const float4 be1 = make_float4(b_e1[0], b_e1[1], b_e1[2], b_e1[3]);
    const float4 be2 = make_float4(b_e2[0], b_e2[1], b_e2[2], b_e2[3]);

    float4 acc0 = make_float4(0.f, 0.f, 0.f, 0.f);
    float4 acc1 = make_float4(0.f, 0.f, 0.f, 0.f);

    for (int j = 0; j < NCG; ++j) {
        const int n = n0 + j;
        const float* __restrict__ xn = x + (size_t)n * CIN * HH * WW;

        // ---- z = 1x1 down conv over halo-2 region ----
        for (int idx = tid; idx < ZH * ZW; idx += 256) {
            const int ly = idx / ZW, lx = idx - (idx / ZW) * ZW;
            const int gy = oy + ly - 2, gx = ox + lx - 2;
            float4 zv = make_float4(0.f, 0.f, 0.f, 0.f);
            if ((unsigned)gy < (unsigned)HH && (unsigned)gx < (unsigned)WW) {
                zv = bdn;
#pragma unroll
                for (int c = 0; c < CIN; ++c)
                    fma4(zv, xn[(c * HH + gy) * WW + gx], wt_down[c]);
            }
            zb[ly][lx] = zv;
        }
        __syncthreads();

        // ---- h1 = silu(3x3 e1) over halo-1 region: 9 row-pairs x 34 cols ----
        for (int t = tid; t < 9 * HW1; t += 256) {
            const int pr = t / HW1;
            const int lx = t - pr * HW1;
            const int ly0 = pr * 2;
            float4 s0 = be1, s1 = be1;
            conv3x3_pair<ZW>(zb, ly0, lx, wt_e1, s0, s1);
            const int gx = ox + lx - 1;
            const int gy0 = oy + ly0 - 1;
            const bool xok = (unsigned)gx < (unsigned)WW;
            const float4 z4 = make_float4(0.f, 0.f, 0.f, 0.f);
            h1b[ly0 + 0][lx] = (xok && (unsigned)(gy0 + 0) < (unsigned)HH) ? silu4(s0) : z4;
            h1b[ly0 + 1][lx] = (xok && (unsigned)(gy0 + 1) < (unsigned)HH) ? silu4(s1) : z4;
        }
        __syncthreads();

        // ---- h2 = silu(3x3 e2) over 8 row-pairs x 32 cols (exact 256), accumulate ----
        {
            const int py0 = (tid >> 5) * 2;
            const int px = tid & 31;
            float4 s0 = be2, s1 = be2;
            conv3x3_pair<HW1>(h1b, py0, px, wt_e2, s0, s1);
            const float4 v0 = silu4(s0), v1 = silu4(s1);
            acc0.x += v0.x; acc0.y += v0.y; acc0.z += v0.z; acc0.w += v0.w;
            acc1.x += v1.x; acc1.y += v1.y; acc1.z += v1.z; acc1.w += v1.w;
        }
        __syncthreads();
    }

    // ---- atomic accumulate into A (pixel-major) ----
    const int py0 = (tid >> 5) * 2;
    const int px = tid & 31;
    const int gy0 = oy + py0, gx = ox + px;
    float* a0 = &A[((size_t)(gy0 + 0) * WW + gx) * 4];
    float* a1 = &A[((size_t)(gy0 + 1) * WW + gx) * 4];
    atomicAdd(a0 + 0, acc0.x); atomicAdd(a0 + 1, acc0.y);
    atomicAdd(a0 + 2, acc0.z); atomicAdd(a0 + 3, acc0.w);
    atomicAdd(a1 + 0, acc1.x); atomicAdd(a1 + 1, acc1.y);
    atomicAdd(a1 + 2, acc1.z); atomicAdd(a1 + 3, acc1.w);
}

__global__ __launch_bounds__(256) void node_kernel(
    const float* __restrict__ x, const float* __restrict__ A,
    const float4* __restrict__ wt,
    const float* __restrict__ b_up, const float* __restrict__ b_n1,
    const float* __restrict__ b_n2, const float* __restrict__ b_r,
    float* __restrict__ out)
{
    __shared__ float4 xa[3][ZH][ZW];   // 33.75 KB: {x0-3, x4-7, Aup0-3}
    __shared__ float4 y1b[HH1][HW1];   // 9.56 KB

    const int tid = threadIdx.x;
    const int ox = blockIdx.x * TW;
    const int oy = blockIdx.y * TH;
    const int n = blockIdx.z;
    const float* __restrict__ xn = x + (size_t)n * CIN * HH * WW;

    const float4* wt_up = wt + W_UP;
    const float4* wt_n1 = wt + W_N1;
    const float4* wt_n2 = wt + W_N2;
    const float4* wt_r  = wt + W_R;

    const float4 bup = make_float4(b_up[0], b_up[1], b_up[2], b_up[3]);
    const float4 bn1 = make_float4(b_n1[0], b_n1[1], b_n1[2], b_n1[3]);
    const float4 bn2r = make_float4(b_n2[0] + b_r[0], b_n2[1] + b_r[1],
                                    b_n2[2] + b_r[2], b_n2[3] + b_r[3]);

    // ---- stage [x || up(A)] tile with halo 2, fusing the 1x1 up conv ----
    for (int idx = tid; idx < ZH * ZW; idx += 256) {
        const int ly = idx / ZW, lx = idx - (idx / ZW) * ZW;
        const int gy = oy + ly - 2, gx = ox + lx - 2;
        float4 g0 = make_float4(0.f, 0.f, 0.f, 0.f);
        float4 g1 = g0, au = g0;
        if ((unsigned)gy < (unsigned)HH && (unsigned)gx < (unsigned)WW) {
            g0 = make_float4(xn[(0 * HH + gy) * WW + gx], xn[(1 * HH + gy) * WW + gx],
                             xn[(2 * HH + gy) * WW + gx], xn[(3 * HH + gy) * WW + gx]);
            g1 = make_float4(xn[(4 * HH + gy) * WW + gx], xn[(5 * HH + gy) * WW + gx],
                             xn[(6 * HH + gy) * WW + gx], xn[(7 * HH + gy) * WW + gx]);
            const float4 a4 = reinterpret_cast<const float4*>(A)[gy * WW + gx];
            au = bup;
#pragma unroll
            for (int e = 0; e < 4; ++e) fma4(au, COMP(a4, e), wt_up[e]);
        }
        xa[0][ly][lx] = g0;
        xa[1][ly][lx] = g1;
        xa[2][ly][lx] = au;
    }
    __syncthreads();

    // ---- y1 = silu(3x3 n1, 12->4) over 9 row-pairs x 34 cols ----
    for (int t = tid; t < 9 * HW1; t += 256) {
        const int pr = t / HW1;
        const int lx = t - pr * HW1;
        const int ly0 = pr * 2;
        float4 s0 = bn1, s1 = bn1;
        conv3x3_pair<ZW>(xa[0], ly0, lx, wt_n1, s0, s1);
        conv3x3_pair<ZW>(xa[1], ly0, lx, wt_n1 + 36, s0, s1);
        conv3x3_pair<ZW>(xa[2], ly0, lx, wt_n1 + 72, s0, s1);
        const int gx = ox + lx - 1;
        const int gy0 = oy + ly0 - 1;
        const bool xok = (unsigned)gx < (unsigned)WW;
        const float4 z4 = make_float4(0.f, 0.f, 0.f, 0.f);
        y1b[ly0 + 0][lx] = (xok && (unsigned)(gy0 + 0) < (unsigned)HH) ? silu4(s0) : z4;
        y1b[ly0 + 1][lx] = (xok && (unsigned)(gy0 + 1) < (unsigned)HH) ? silu4(s1) : z4;
    }
    __syncthreads();

    // ---- out = 3x3 n2 (y1) + 1x1 r (x), 8 row-pairs x 32 cols (exact 256) ----
    {
        const int py0 = (tid >> 5) * 2;
        const int px = tid & 31;
        float4 s0 = bn2r, s1 = bn2r;
        conv3x3_pair<HW1>(y1b, py0, px, wt_n2, s0, s1);
        // residual 1x1 on x (groups 0,1), tile-center offset +2
#pragma unroll
        for (int g = 0; g < 2; ++g) {
            const float4 c0 = xa[g][py0 + 2][px + 2];
            const float4 c1 = xa[g][py0 + 3][px + 2];
#pragma unroll
            for (int ci = 0; ci < 4; ++ci) {
                const float4 w4 = wt_r[g * 4 + ci];
                fma4(s0, COMP(c0, ci), w4);
                fma4(s1, COMP(c1, ci), w4);
            }
        }
        const int gy0 = oy + py0, gx = ox + px;
#pragma unroll
        for (int o = 0; o < 4; ++o) {
            out[(((size_t)n * DD + o) * HH + gy0 + 0) * WW + gx] = COMP(s0, o);
            out[(((size_t)n * DD + o) * HH + gy0 + 1) * WW + gx] = COMP(s1, o);
        }
    }
}

extern "C" void kernel_launch(void* const* d_in, const int* in_sizes, int n_in,
                              void* d_out, int out_size, void* d_ws, size_t ws_size,
                              hipStream_t stream) {
    const float* x      = (const float*)d_in[0];
    const float* w_down = (const float*)d_in[1];
    const float* b_down = (const float*)d_in[2];
    const float* w_e1   = (const float*)d_in[3];
    const float* b_e1   = (const float*)d_in[4];
    const float* w_e2   = (const float*)d_in[5];
    const float* b_e2   = (const float*)d_in[6];
    const float* w_up   = (const float*)d_in[7];
    const float* b_up   = (const float*)d_in[8];
    const float* w_n1   = (const float*)d_in[9];
    const float* b_n1   = (const float*)d_in[10];
    const float* w_n2   = (const float*)d_in[11];
    const float* b_n2   = (const float*)d_in[12];
    const float* w_r    = (const float*)d_in[13];
    const float* b_r    = (const float*)d_in[14];
    float* out = (float*)d_out;

    float* A = (float*)d_ws;                               // 1 MiB, pixel-major
    float4* wt = (float4*)((float*)d_ws + 4 * HH * WW);    // 236 float4

    zero_kernel<<<dim3(256), dim3(256), 0, stream>>>(A);
    prep_kernel<<<dim3(1), dim3(128), 0, stream>>>(w_down, w_e1, w_e2, w_up,
                                                   w_n1, w_n2, w_r, wt);

    edge_kernel<<<dim3(WW / TW, HH / TH, NCELL / NCG), dim3(256), 0, stream>>>(
        x, wt, b_down, b_e1, b_e2, A);

    node_kernel<<<dim3(WW / TW, HH / TH, NCELL), dim3(256), 0, stream>>>(
        x, A, wt, b_up, b_n1, b_n2, b_r, out);
}

// Round 6
// 471.433 us; speedup vs baseline: 1.8926x; 1.4075x over previous
//
#include <hip/hip_runtime.h>
#include <hip/hip_bf16.h>

#define NCELL 64
#define CIN 8
#define EE 4
#define DD 4
#define HH 256
#define WW 256

#define EBH 16          // edge band height
#define NBH 22          // node band height
#define NBANDS_E (HH / EBH)           // 16
#define NBANDS_N ((HH + NBH - 1) / NBH) // 12

#define SLOT(r) (((r) + 300) % 3)
#define COMP(v,i) ((i)==0?(v).x:(i)==1?(v).y:(i)==2?(v).z:(v).w)

__device__ __forceinline__ float silu1(float v) { return v / (1.0f + __expf(-v)); }
__device__ __forceinline__ float4 silu4f(const float a[4]) {
    return make_float4(silu1(a[0]), silu1(a[1]), silu1(a[2]), silu1(a[3]));
}
__device__ __forceinline__ float4 f4z() { return make_float4(0.f, 0.f, 0.f, 0.f); }

// 3x3 conv accumulate for one 4-channel input group.
// L/Cc/R: rows dy=0..2 at columns x-1, x, x+1 (4 packed channels each).
// w: conv weights [o][i][3][3] flattened; ostride = i_total*9; ibase = first input ch.
__device__ __forceinline__ void conv_group(const float4* L, const float4* Cc, const float4* R,
                                           const float* __restrict__ w, int ostride, int ibase,
                                           float acc[4]) {
#pragma unroll
    for (int dy = 0; dy < 3; ++dy) {
#pragma unroll
        for (int ci = 0; ci < 4; ++ci) {
            const float aL = COMP(L[dy], ci);
            const float aC = COMP(Cc[dy], ci);
            const float aR = COMP(R[dy], ci);
#pragma unroll
            for (int o = 0; o < 4; ++o) {
                const int base = o * ostride + (ibase + ci) * 9 + dy * 3;
                acc[o] = fmaf(aL, w[base + 0], acc[o]);
                acc[o] = fmaf(aC, w[base + 1], acc[o]);
                acc[o] = fmaf(aR, w[base + 2], acc[o]);
            }
        }
    }
}

__global__ __launch_bounds__(256) void zero_kernel(float* __restrict__ p) {
    int i = blockIdx.x * 256 + threadIdx.x;
    reinterpret_cast<float4*>(p)[i] = f4z();
}

// ---------------- edge pass: rolling rows, one thread per column ----------------
__global__ __launch_bounds__(256) void edge_kernel(
    const float* __restrict__ x,
    const float* __restrict__ w_down, const float* __restrict__ b_down,
    const float* __restrict__ w_e1, const float* __restrict__ b_e1,
    const float* __restrict__ w_e2, const float* __restrict__ b_e2,
    float* __restrict__ A)   // pixel-major: A[(y*WW+x)*4 + e]
{
    __shared__ float4 ZB[3][WW + 2];   // z rows, circular
    __shared__ float4 HB[3][WW + 2];   // h1 rows, circular

    const int tid = threadIdx.x;
    const int c = tid + 1;             // LDS col (halo at 0 and WW+1)
    const int y0 = blockIdx.x * EBH;
    const int n = blockIdx.y;
    const float* __restrict__ xn = x + (size_t)n * CIN * HH * WW;

    if (tid < 3) {
        ZB[tid][0] = f4z(); ZB[tid][WW + 1] = f4z();
        HB[tid][0] = f4z(); HB[tid][WW + 1] = f4z();
    }
    __syncthreads();

    float4 z0 = f4z(), z1 = f4z(), z2 = f4z();   // own-col z rows (r-2, r-1, r)
    float4 p0 = f4z(), p1 = f4z(), p2 = f4z();   // own-col h1 rows

    for (int k = 0; k < EBH + 4; ++k) {
        const int zr = y0 - 2 + k;

        // ---- stage: z(zr) = 1x1 down conv ----
        float4 zn = f4z();
        if ((unsigned)zr < (unsigned)HH) {
            float xv[CIN];
#pragma unroll
            for (int i = 0; i < CIN; ++i) xv[i] = xn[(i * HH + zr) * WW + tid];
            float za[4];
#pragma unroll
            for (int e = 0; e < 4; ++e) {
                float s = b_down[e];
#pragma unroll
                for (int i = 0; i < CIN; ++i) s = fmaf(xv[i], w_down[e * CIN + i], s);
                za[e] = s;
            }
            zn = make_float4(za[0], za[1], za[2], za[3]);
        }
        z0 = z1; z1 = z2; z2 = zn;
        ZB[SLOT(zr)][c] = zn;
        __syncthreads();

        // ---- h1(zr-1) = silu(3x3 e1 on z) ----
        {
            const int hr = zr - 1;
            float4 hn = f4z();
            if (k >= 2 && (unsigned)hr < (unsigned)HH) {
                const int sA = SLOT(hr - 1), sB = SLOT(hr), sC = SLOT(hr + 1);
                float4 L[3] = { ZB[sA][c - 1], ZB[sB][c - 1], ZB[sC][c - 1] };
                float4 R[3] = { ZB[sA][c + 1], ZB[sB][c + 1], ZB[sC][c + 1] };
                float4 Cc[3] = { z0, z1, z2 };
                float acc[4] = { b_e1[0], b_e1[1], b_e1[2], b_e1[3] };
                conv_group(L, Cc, R, w_e1, 36, 0, acc);
                hn = silu4f(acc);
            }
            p0 = p1; p1 = p2; p2 = hn;
            HB[SLOT(hr)][c] = hn;
        }
        __syncthreads();

        // ---- h2(zr-2) = silu(3x3 e2 on h1), atomic accumulate into A ----
        if (k >= 4) {
            const int orow = zr - 2;
            const int sA = SLOT(orow - 1), sB = SLOT(orow), sC = SLOT(orow + 1);
            float4 L[3] = { HB[sA][c - 1], HB[sB][c - 1], HB[sC][c - 1] };
            float4 R[3] = { HB[sA][c + 1], HB[sB][c + 1], HB[sC][c + 1] };
            float4 Cc[3] = { p0, p1, p2 };
            float acc[4] = { b_e2[0], b_e2[1], b_e2[2], b_e2[3] };
            conv_group(L, Cc, R, w_e2, 36, 0, acc);
            const float4 v = silu4f(acc);
            float* ap = &A[((size_t)orow * WW + tid) * 4];
            atomicAdd(ap + 0, v.x);
            atomicAdd(ap + 1, v.y);
            atomicAdd(ap + 2, v.z);
            atomicAdd(ap + 3, v.w);
        }
    }
}

// ---------------- node pass: rolling rows, one thread per column ----------------
__global__ __launch_bounds__(256) void node_kernel(
    const float* __restrict__ x, const float* __restrict__ A,
    const float* __restrict__ w_up, const float* __restrict__ b_up,
    const float* __restrict__ w_n1, const float* __restrict__ b_n1,
    const float* __restrict__ w_n2, const float* __restrict__ b_n2,
    const float* __restrict__ w_r, const float* __restrict__ b_r,
    float* __restrict__ out)
{
    __shared__ float4 SB[3][WW + 2][3];  // [slot][col][group]: {x0-3, x4-7, Aup}
    __shared__ float4 YB[3][WW + 2];     // y1 rows, circular

    const int tid = threadIdx.x;
    const int c = tid + 1;
    const int y0 = blockIdx.x * NBH;
    const int h = min(NBH, HH - y0);
    const int n = blockIdx.y;
    const float* __restrict__ xn = x + (size_t)n * CIN * HH * WW;

    if (tid < 3) {
#pragma unroll
        for (int j = 0; j < 3; ++j) { SB[tid][0][j] = f4z(); SB[tid][WW + 1][j] = f4z(); }
        YB[tid][0] = f4z(); YB[tid][WW + 1] = f4z();
    }
    __syncthreads();

    float4 r0[3], r1[3], r2[3];          // own-col S rows (or, or+1, or+2)
    float4 q0 = f4z(), q1 = f4z(), q2 = f4z();  // own-col y1 rows
#pragma unroll
    for (int j = 0; j < 3; ++j) { r0[j] = f4z(); r1[j] = f4z(); r2[j] = f4z(); }

    for (int k = 0; k < h + 4; ++k) {
        const int zr = y0 - 2 + k;

        // ---- stage: S(zr) = [x(8ch) || up(A)(4ch)] ----
        float4 Sn[3] = { f4z(), f4z(), f4z() };
        if ((unsigned)zr < (unsigned)HH) {
            float xv[CIN];
#pragma unroll
            for (int i = 0; i < CIN; ++i) xv[i] = xn[(i * HH + zr) * WW + tid];
            Sn[0] = make_float4(xv[0], xv[1], xv[2], xv[3]);
            Sn[1] = make_float4(xv[4], xv[5], xv[6], xv[7]);
            const float4 a4 = reinterpret_cast<const float4*>(A)[zr * WW + tid];
            float au[4];
#pragma unroll
            for (int o = 0; o < 4; ++o) {
                float s = b_up[o];
#pragma unroll
                for (int e = 0; e < 4; ++e) s = fmaf(COMP(a4, e), w_up[o * EE + e], s);
                au[o] = s;
            }
            Sn[2] = make_float4(au[0], au[1], au[2], au[3]);
        }
#pragma unroll
        for (int j = 0; j < 3; ++j) { r0[j] = r1[j]; r1[j] = r2[j]; r2[j] = Sn[j]; }
        {
            const int s = SLOT(zr);
#pragma unroll
            for (int j = 0; j < 3; ++j) SB[s][c][j] = Sn[j];
        }
        __syncthreads();

        // ---- y1(zr-1) = silu(3x3 n1, 12ch -> 4ch) ----
        {
            const int hr = zr - 1;
            float4 yn = f4z();
            if (k >= 2 && (unsigned)hr < (unsigned)HH) {
                const int sA = SLOT(hr - 1), sB = SLOT(hr), sC = SLOT(hr + 1);
                float acc[4] = { b_n1[0], b_n1[1], b_n1[2], b_n1[3] };
#pragma unroll
                for (int j = 0; j < 3; ++j) {
                    float4 L[3] = { SB[sA][c - 1][j], SB[sB][c - 1][j], SB[sC][c - 1][j] };
                    float4 R[3] = { SB[sA][c + 1][j], SB[sB][c + 1][j], SB[sC][c + 1][j] };
                    float4 Cc[3] = { r0[j], r1[j], r2[j] };
                    conv_group(L, Cc, R, w_n1, 108, j * 4, acc);
                }
                yn = silu4f(acc);
            }
            q0 = q1; q1 = q2; q2 = yn;
            YB[SLOT(hr)][c] = yn;
        }
        __syncthreads();

        // ---- out(zr-2) = 3x3 n2 (y1) + 1x1 r (x) ----
        if (k >= 4) {
            const int orow = zr - 2;
            const int sA = SLOT(orow - 1), sB = SLOT(orow), sC = SLOT(orow + 1);
            float4 L[3] = { YB[sA][c - 1], YB[sB][c - 1], YB[sC][c - 1] };
            float4 R[3] = { YB[sA][c + 1], YB[sB][c + 1], YB[sC][c + 1] };
            float4 Cc[3] = { q0, q1, q2 };
            float acc[4] = { b_n2[0] + b_r[0], b_n2[1] + b_r[1],
                             b_n2[2] + b_r[2], b_n2[3] + b_r[3] };
            conv_group(L, Cc, R, w_n2, 36, 0, acc);
            // residual 1x1 on x: S row `orow` own col = r0 groups 0,1
#pragma unroll
            for (int g = 0; g < 2; ++g) {
                const float4 xr = r0[g];
#pragma unroll
                for (int ci = 0; ci < 4; ++ci) {
                    const float a = COMP(xr, ci);
#pragma unroll
                    for (int o = 0; o < 4; ++o)
                        acc[o] = fmaf(a, w_r[o * CIN + g * 4 + ci], acc[o]);
                }
            }
#pragma unroll
            for (int o = 0; o < 4; ++o)
                out[(((size_t)n * DD + o) * HH + orow) * WW + tid] = acc[o];
        }
    }
}

extern "C" void kernel_launch(void* const* d_in, const int* in_sizes, int n_in,
                              void* d_out, int out_size, void* d_ws, size_t ws_size,
                              hipStream_t stream) {
    const float* x      = (const float*)d_in[0];
    const float* w_down = (const float*)d_in[1];
    const float* b_down = (const float*)d_in[2];
    const float* w_e1   = (const float*)d_in[3];
    const float* b_e1   = (const float*)d_in[4];
    const float* w_e2   = (const float*)d_in[5];
    const float* b_e2   = (const float*)d_in[6];
    const float* w_up   = (const float*)d_in[7];
    const float* b_up   = (const float*)d_in[8];
    const float* w_n1   = (const float*)d_in[9];
    const float* b_n1   = (const float*)d_in[10];
    const float* w_n2   = (const float*)d_in[11];
    const float* b_n2   = (const float*)d_in[12];
    const float* w_r    = (const float*)d_in[13];
    const float* b_r    = (const float*)d_in[14];
    float* out = (float*)d_out;

    float* A = (float*)d_ws;  // pixel-major (HH*WW, 4) floats = 1 MiB

    zero_kernel<<<dim3(256), dim3(256), 0, stream>>>(A);

    edge_kernel<<<dim3(NBANDS_E, NCELL), dim3(256), 0, stream>>>(
        x, w_down, b_down, w_e1, b_e1, w_e2, b_e2, A);

    node_kernel<<<dim3(NBANDS_N, NCELL), dim3(256), 0, stream>>>(
        x, A, w_up, b_up, w_n1, b_n1, w_n2, b_n2, w_r, b_r, out);
}

// Round 7
// 311.456 us; speedup vs baseline: 2.8647x; 1.5136x over previous
//
#include <hip/hip_runtime.h>
#include <hip/hip_bf16.h>

#define NCELL 64
#define CIN 8
#define EE 4
#define DD 4
#define HH 256
#define WW 256

#define EBH 32                         // edge band height
#define NBH 26                         // node band height
#define NBANDS_E (HH / EBH)            // 8
#define NBANDS_N ((HH + NBH - 1) / NBH) // 10
#define NSTRIP 5                       // 5 strips x 60 payload cols >= 256

__device__ __forceinline__ float4 f4z() { return make_float4(0.f, 0.f, 0.f, 0.f); }
__device__ __forceinline__ float silu1(float v) { return v / (1.0f + __expf(-v)); }
__device__ __forceinline__ float4 silu4f(const float a[4]) {
    return make_float4(silu1(a[0]), silu1(a[1]), silu1(a[2]), silu1(a[3]));
}
// value from lane-1 (left column). boundary lanes get self (garbage) -> only feeds
// discarded halo outputs.
__device__ __forceinline__ float4 shfL(float4 v) {
    return make_float4(__shfl_up(v.x, 1), __shfl_up(v.y, 1),
                       __shfl_up(v.z, 1), __shfl_up(v.w, 1));
}
__device__ __forceinline__ float4 shfR(float4 v) {
    return make_float4(__shfl_down(v.x, 1), __shfl_down(v.y, 1),
                       __shfl_down(v.z, 1), __shfl_down(v.w, 1));
}

#define COMP(v,i) ((i)==0?(v).x:(i)==1?(v).y:(i)==2?(v).z:(v).w)

// 3x3 conv accumulate, one 4-ch input group: L/C/R = rows dy=0..2 at cols x-1,x,x+1.
// w: [o][i][3][3] flattened; ostride = i_total*9; ibase = first input channel.
__device__ __forceinline__ void conv_group(const float4* L, const float4* C, const float4* R,
                                           const float* __restrict__ w, int ostride, int ibase,
                                           float acc[4]) {
#pragma unroll
    for (int dy = 0; dy < 3; ++dy) {
#pragma unroll
        for (int ci = 0; ci < 4; ++ci) {
            const float aL = COMP(L[dy], ci);
            const float aC = COMP(C[dy], ci);
            const float aR = COMP(R[dy], ci);
#pragma unroll
            for (int o = 0; o < 4; ++o) {
                const int base = o * ostride + (ibase + ci) * 9 + dy * 3;
                acc[o] = fmaf(aL, w[base + 0], acc[o]);
                acc[o] = fmaf(aC, w[base + 1], acc[o]);
                acc[o] = fmaf(aR, w[base + 2], acc[o]);
            }
        }
    }
}

// ---------------- edge pass: one wave per (band, strip, cell), registers only ----
__global__ __launch_bounds__(256) void edge_kernel(
    const float* __restrict__ x,
    const float* __restrict__ w_down, const float* __restrict__ b_down,
    const float* __restrict__ w_e1, const float* __restrict__ b_e1,
    const float* __restrict__ w_e2, const float* __restrict__ b_e2,
    float4* __restrict__ P)   // per-cell partials: P[n*65536 + y*256 + x]
{
    const int lane = threadIdx.x & 63;
    const int wv = threadIdx.x >> 6;
    const int y0 = blockIdx.x * EBH;
    const int s = blockIdx.y;
    const int n = blockIdx.z * 4 + wv;
    const int cx = s * 60 + lane - 2;
    const bool colok = (unsigned)cx < (unsigned)WW;
    const bool payload = (lane >= 2) && (lane < 62) && colok;
    const float* __restrict__ xn = x + (size_t)n * CIN * HH * WW;

    const float bd0 = b_down[0], bd1 = b_down[1], bd2 = b_down[2], bd3 = b_down[3];
    const float be10 = b_e1[0], be11 = b_e1[1], be12 = b_e1[2], be13 = b_e1[3];
    const float be20 = b_e2[0], be21 = b_e2[1], be22 = b_e2[2], be23 = b_e2[3];

    float4 za0 = f4z(), za1 = f4z(), za2 = f4z();   // z rows, own col
    float4 zb0 = f4z(), zb1 = f4z(), zb2 = f4z();   // left col
    float4 zc0 = f4z(), zc1 = f4z(), zc2 = f4z();   // right col
    float4 ha0 = f4z(), ha1 = f4z(), ha2 = f4z();   // h1 rows
    float4 hb0 = f4z(), hb1 = f4z(), hb2 = f4z();
    float4 hc0 = f4z(), hc1 = f4z(), hc2 = f4z();

    for (int k = 0; k < EBH + 4; ++k) {
        const int zr = y0 - 2 + k;

        // ---- stage z(zr) = 1x1 down conv ----
        float4 zn = f4z();
        if ((unsigned)zr < (unsigned)HH) {          // uniform
            if (colok) {
                float a0 = bd0, a1 = bd1, a2 = bd2, a3 = bd3;
#pragma unroll
                for (int i = 0; i < CIN; ++i) {
                    const float xv = xn[((size_t)i * HH + zr) * WW + cx];
                    a0 = fmaf(xv, w_down[0 * CIN + i], a0);
                    a1 = fmaf(xv, w_down[1 * CIN + i], a1);
                    a2 = fmaf(xv, w_down[2 * CIN + i], a2);
                    a3 = fmaf(xv, w_down[3 * CIN + i], a3);
                }
                zn = make_float4(a0, a1, a2, a3);
            }
        }
        za0 = za1; za1 = za2; za2 = zn;
        zb0 = zb1; zb1 = zb2; zb2 = shfL(zn);
        zc0 = zc1; zc1 = zc2; zc2 = shfR(zn);

        // ---- h1(zr-1) = silu(3x3 e1) ----
        if (k >= 2) {                                // uniform
            float acc[4] = { be10, be11, be12, be13 };
            {
                float4 L[3] = { zb0, zb1, zb2 };
                float4 C[3] = { za0, za1, za2 };
                float4 R[3] = { zc0, zc1, zc2 };
                conv_group(L, C, R, w_e1, 36, 0, acc);
            }
            const int hr = zr - 1;
            const float4 hn = ((unsigned)hr < (unsigned)HH && colok) ? silu4f(acc) : f4z();
            ha0 = ha1; ha1 = ha2; ha2 = hn;
            hb0 = hb1; hb1 = hb2; hb2 = shfL(hn);
            hc0 = hc1; hc1 = hc2; hc2 = shfR(hn);
        }

        // ---- h2(zr-2) = silu(3x3 e2), write partial ----
        if (k >= 4) {                                // uniform
            float acc[4] = { be20, be21, be22, be23 };
            {
                float4 L[3] = { hb0, hb1, hb2 };
                float4 C[3] = { ha0, ha1, ha2 };
                float4 R[3] = { hc0, hc1, hc2 };
                conv_group(L, C, R, w_e2, 36, 0, acc);
            }
            if (payload) {
                const int orow = zr - 2;
                P[(size_t)n * (HH * WW) + orow * WW + cx] = silu4f(acc);
            }
        }
    }
}

// ---------------- reduce over cells: A = sum_n P[n] ----------------
__global__ __launch_bounds__(256) void reduce_kernel(
    const float4* __restrict__ P, float4* __restrict__ A4)
{
    const int p = blockIdx.x * 256 + threadIdx.x;   // < 65536
    float4 a = f4z(), b = f4z(), c = f4z(), d = f4z();
#pragma unroll
    for (int nn = 0; nn < NCELL; nn += 4) {
        const float4 v0 = P[(size_t)(nn + 0) * (HH * WW) + p];
        const float4 v1 = P[(size_t)(nn + 1) * (HH * WW) + p];
        const float4 v2 = P[(size_t)(nn + 2) * (HH * WW) + p];
        const float4 v3 = P[(size_t)(nn + 3) * (HH * WW) + p];
        a.x += v0.x; a.y += v0.y; a.z += v0.z; a.w += v0.w;
        b.x += v1.x; b.y += v1.y; b.z += v1.z; b.w += v1.w;
        c.x += v2.x; c.y += v2.y; c.z += v2.z; c.w += v2.w;
        d.x += v3.x; d.y += v3.y; d.z += v3.z; d.w += v3.w;
    }
    A4[p] = make_float4(a.x + b.x + c.x + d.x, a.y + b.y + c.y + d.y,
                        a.z + b.z + c.z + d.z, a.w + b.w + c.w + d.w);
}

// ---------------- node pass: one wave per (band, strip, cell) ----------------
__global__ __launch_bounds__(256) void node_kernel(
    const float* __restrict__ x, const float* __restrict__ A,
    const float* __restrict__ w_up, const float* __restrict__ b_up,
    const float* __restrict__ w_n1, const float* __restrict__ b_n1,
    const float* __restrict__ w_n2, const float* __restrict__ b_n2,
    const float* __restrict__ w_r, const float* __restrict__ b_r,
    float* __restrict__ out)
{
    const int lane = threadIdx.x & 63;
    const int wv = threadIdx.x >> 6;
    const int y0 = blockIdx.x * NBH;
    const int h = min(NBH, HH - y0);
    const int s = blockIdx.y;
    const int n = blockIdx.z * 4 + wv;
    const int cx = s * 60 + lane - 2;
    const bool colok = (unsigned)cx < (unsigned)WW;
    const bool payload = (lane >= 2) && (lane < 62) && colok;
    const float* __restrict__ xn = x + (size_t)n * CIN * HH * WW;
    const float4* __restrict__ A4 = reinterpret_cast<const float4*>(A);

    const float bu0 = b_up[0], bu1 = b_up[1], bu2 = b_up[2], bu3 = b_up[3];
    const float bn10 = b_n1[0], bn11 = b_n1[1], bn12 = b_n1[2], bn13 = b_n1[3];
    const float br0 = b_n2[0] + b_r[0], br1 = b_n2[1] + b_r[1];
    const float br2 = b_n2[2] + b_r[2], br3 = b_n2[3] + b_r[3];

    float4 sa[3][3];   // [group][row] own-col S rows; static-indexed only
#pragma unroll
    for (int g = 0; g < 3; ++g) { sa[g][0] = f4z(); sa[g][1] = f4z(); sa[g][2] = f4z(); }
    float4 ya[3] = { f4z(), f4z(), f4z() };   // y1 rows own
    float4 yb[3] = { f4z(), f4z(), f4z() };   // left
    float4 yc[3] = { f4z(), f4z(), f4z() };   // right

    for (int k = 0; k < h + 4; ++k) {
        const int zr = y0 - 2 + k;

        // ---- stage S(zr) = [x(2 groups) || up(A)] ----
        float4 Sn0 = f4z(), Sn1 = f4z(), Sn2 = f4z();
        if ((unsigned)zr < (unsigned)HH) {          // uniform
            if (colok) {
                float xv[CIN];
#pragma unroll
                for (int i = 0; i < CIN; ++i) xv[i] = xn[((size_t)i * HH + zr) * WW + cx];
                Sn0 = make_float4(xv[0], xv[1], xv[2], xv[3]);
                Sn1 = make_float4(xv[4], xv[5], xv[6], xv[7]);
                const float4 a4 = A4[zr * WW + cx];
                float u0 = bu0, u1 = bu1, u2 = bu2, u3 = bu3;
#pragma unroll
                for (int e = 0; e < 4; ++e) {
                    const float av = COMP(a4, e);
                    u0 = fmaf(av, w_up[0 * EE + e], u0);
                    u1 = fmaf(av, w_up[1 * EE + e], u1);
                    u2 = fmaf(av, w_up[2 * EE + e], u2);
                    u3 = fmaf(av, w_up[3 * EE + e], u3);
                }
                Sn2 = make_float4(u0, u1, u2, u3);
            }
        }
        sa[0][0] = sa[0][1]; sa[0][1] = sa[0][2]; sa[0][2] = Sn0;
        sa[1][0] = sa[1][1]; sa[1][1] = sa[1][2]; sa[1][2] = Sn1;
        sa[2][0] = sa[2][1]; sa[2][1] = sa[2][2]; sa[2][2] = Sn2;

        // ---- y1(zr-1) = silu(3x3 n1, 12ch->4ch) ----
        if (k >= 2) {                                // uniform
            float acc[4] = { bn10, bn11, bn12, bn13 };
#pragma unroll
            for (int g = 0; g < 3; ++g) {
                float4 L[3] = { shfL(sa[g][0]), shfL(sa[g][1]), shfL(sa[g][2]) };
                float4 R[3] = { shfR(sa[g][0]), shfR(sa[g][1]), shfR(sa[g][2]) };
                conv_group(L, sa[g], R, w_n1, 108, 4 * g, acc);
            }
            const int hr = zr - 1;
            const float4 yn = ((unsigned)hr < (unsigned)HH && colok) ? silu4f(acc) : f4z();
            ya[0] = ya[1]; ya[1] = ya[2]; ya[2] = yn;
            yb[0] = yb[1]; yb[1] = yb[2]; yb[2] = shfL(yn);
            yc[0] = yc[1]; yc[1] = yc[2]; yc[2] = shfR(yn);
        }

        // ---- out(zr-2) = 3x3 n2 (y1) + 1x1 r (x) ----
        if (k >= 4) {                                // uniform
            float acc[4] = { br0, br1, br2, br3 };
            conv_group(yb, ya, yc, w_n2, 36, 0, acc);
            // residual 1x1 on x: S row (zr-2) own col = sa[0][0], sa[1][0]
#pragma unroll
            for (int g = 0; g < 2; ++g) {
                const float4 xr = (g == 0) ? sa[0][0] : sa[1][0];
#pragma unroll
                for (int ci = 0; ci < 4; ++ci) {
                    const float a = COMP(xr, ci);
                    acc[0] = fmaf(a, w_r[0 * CIN + g * 4 + ci], acc[0]);
                    acc[1] = fmaf(a, w_r[1 * CIN + g * 4 + ci], acc[1]);
                    acc[2] = fmaf(a, w_r[2 * CIN + g * 4 + ci], acc[2]);
                    acc[3] = fmaf(a, w_r[3 * CIN + g * 4 + ci], acc[3]);
                }
            }
            if (payload) {
                const int orow = zr - 2;
#pragma unroll
                for (int o = 0; o < 4; ++o)
                    out[(((size_t)n * DD + o) * HH + orow) * WW + cx] = acc[o];
            }
        }
    }
}

extern "C" void kernel_launch(void* const* d_in, const int* in_sizes, int n_in,
                              void* d_out, int out_size, void* d_ws, size_t ws_size,
                              hipStream_t stream) {
    const float* x      = (const float*)d_in[0];
    const float* w_down = (const float*)d_in[1];
    const float* b_down = (const float*)d_in[2];
    const float* w_e1   = (const float*)d_in[3];
    const float* b_e1   = (const float*)d_in[4];
    const float* w_e2   = (const float*)d_in[5];
    const float* b_e2   = (const float*)d_in[6];
    const float* w_up   = (const float*)d_in[7];
    const float* b_up   = (const float*)d_in[8];
    const float* w_n1   = (const float*)d_in[9];
    const float* b_n1   = (const float*)d_in[10];
    const float* w_n2   = (const float*)d_in[11];
    const float* b_n2   = (const float*)d_in[12];
    const float* w_r    = (const float*)d_in[13];
    const float* b_r    = (const float*)d_in[14];
    float* out = (float*)d_out;

    // Per-cell partials exactly fill d_out (64*256*256 float4 == out_size floats);
    // node_kernel overwrites d_out with the final output afterwards.
    float4* P = (float4*)d_out;
    float* A  = (float*)d_ws;   // 1 MiB pixel-major aggregate

    edge_kernel<<<dim3(NBANDS_E, NSTRIP, NCELL / 4), dim3(256), 0, stream>>>(
        x, w_down, b_down, w_e1, b_e1, w_e2, b_e2, P);

    reduce_kernel<<<dim3(HH * WW / 256), dim3(256), 0, stream>>>(P, (float4*)A);

    node_kernel<<<dim3(NBANDS_N, NSTRIP, NCELL / 4), dim3(256), 0, stream>>>(
        x, A, w_up, b_up, w_n1, b_n1, w_n2, b_n2, w_r, b_r, out);
}